// Round 18
// baseline (285.304 us; speedup 1.0000x reference)
//
#include <hip/hip_runtime.h>
#include <hip/hip_fp16.h>

#define NEG_SLOPE 0.2f

typedef _Float16 half8_t __attribute__((ext_vector_type(8)));
typedef _Float16 half4_t __attribute__((ext_vector_type(4)));
typedef float f32x4 __attribute__((ext_vector_type(4)));

__device__ __forceinline__ __half2 u2h2(unsigned u) {
  union { unsigned u; __half2 h; } cv; cv.u = u; return cv.h;
}
__device__ __forceinline__ unsigned h22u(__half2 h) {
  union { unsigned u; __half2 h; } cv; cv.h = h; return cv.u;
}

// ---------- x (f32) -> fp16 table, float4-vectorized ----------
__global__ void cvt_f2h_kernel(const float* __restrict__ in, _Float16* __restrict__ out, int n4) {
  int i = blockIdx.x * blockDim.x + threadIdx.x;
  if (i >= n4) return;
  float4 v = ((const float4*)in)[i];
  half4_t h = { (_Float16)v.x, (_Float16)v.y, (_Float16)v.z, (_Float16)v.w };
  ((half4_t*)out)[i] = h;
}

// ---------- dual-output MFMA GEMM (fp16 in, f32 acc): Y1(fp16)=X@W1, Y2(f32)=X@W2 ----------
// 4 waves/block, each wave: 16 rows x H cols via mfma_f32_16x16x32_f16.
// W staged TRANSPOSED fp16 in LDS ([H][K+4] pad -> 8B b-frag reads, ~2-way banks).
// Fragment maps: A row=lane&15, k = kt*32 + (lane>>4)*4 + (j&3) + (j>>2)*16
// (split-4+4 per 16-k half, per m156/m162 tr-read structure); C/D col=lane&15,
// row=(lane>>4)*4+j (m89-verified, dtype-independent). Fallback if refcheck
// fails: contiguous-8 (k = kt*32 + (lane>>4)*8 + j).
template<int K, int H>
__global__ __launch_bounds__(256) void gemm2_mfma_kernel(const _Float16* __restrict__ Xh,
                                                         const float* __restrict__ W1,
                                                         const float* __restrict__ W2,
                                                         __half* __restrict__ Y1,
                                                         float* __restrict__ Y2, int n) {
  constexpr int KP = K + 4;   // padded LDS stride (halves); KP*2 % 8 == 0
  constexpr int KT = K / 32;  // MFMA K-steps
  constexpr int CT = H / 16;  // col tiles
  __shared__ _Float16 Ws1[H * KP];
  __shared__ _Float16 Ws2[H * KP];
  const int tid = threadIdx.x;
  // stage W transposed (consecutive tid -> consecutive k, same h: 2B-stride writes)
  for (int idx = tid; idx < K * H; idx += 256) {
    int k = idx % K, h = idx / K;
    Ws1[h * KP + k] = (_Float16)W1[(size_t)k * H + h];
    Ws2[h * KP + k] = (_Float16)W2[(size_t)k * H + h];
  }
  __syncthreads();
  const int wv = tid >> 6, lane = tid & 63;
  const int q = lane >> 4, c = lane & 15;
  const int r0 = blockIdx.x * 64 + wv * 16;
  if (r0 >= n) return;
  int arow = r0 + c; if (arow >= n) arow = n - 1;
  const _Float16* Xrow = Xh + (size_t)arow * K;
  half8_t A[KT];
#pragma unroll
  for (int kt = 0; kt < KT; ++kt) {
    half4_t lo = *(const half4_t*)(Xrow + kt * 32 + q * 4);
    half4_t hi = *(const half4_t*)(Xrow + kt * 32 + 16 + q * 4);
    A[kt] = __builtin_shufflevector(lo, hi, 0, 1, 2, 3, 4, 5, 6, 7);
  }
#pragma unroll
  for (int ct = 0; ct < CT; ++ct) {
    const int col = ct * 16 + c;
    f32x4 acc1 = {0.f, 0.f, 0.f, 0.f};
    f32x4 acc2 = {0.f, 0.f, 0.f, 0.f};
#pragma unroll
    for (int kt = 0; kt < KT; ++kt) {
      const _Float16* w1p = &Ws1[col * KP + kt * 32 + q * 4];
      const _Float16* w2p = &Ws2[col * KP + kt * 32 + q * 4];
      half4_t b1lo = *(const half4_t*)w1p;
      half4_t b1hi = *(const half4_t*)(w1p + 16);
      half4_t b2lo = *(const half4_t*)w2p;
      half4_t b2hi = *(const half4_t*)(w2p + 16);
      half8_t B1 = __builtin_shufflevector(b1lo, b1hi, 0, 1, 2, 3, 4, 5, 6, 7);
      half8_t B2 = __builtin_shufflevector(b2lo, b2hi, 0, 1, 2, 3, 4, 5, 6, 7);
      acc1 = __builtin_amdgcn_mfma_f32_16x16x32_f16(A[kt], B1, acc1, 0, 0, 0);
      acc2 = __builtin_amdgcn_mfma_f32_16x16x32_f16(A[kt], B2, acc2, 0, 0, 0);
    }
#pragma unroll
    for (int j = 0; j < 4; ++j) {
      int rowg = r0 + q * 4 + j;
      if (rowg < n) {
        Y1[(size_t)rowg * H + col] = __float2half(acc1[j]);
        Y2[(size_t)rowg * H + col] = acc2[j];
      }
    }
  }
}

// ---------- CSR build: histogram of dst ----------
__global__ void hist_kernel(const int* __restrict__ ei, int* __restrict__ deg, int nE, int nN) {
  int t = blockIdx.x * blockDim.x + threadIdx.x;
  if (t >= nE + nN) return;
  int d = (t < nE) ? ei[nE + t] : (t - nE);
  atomicAdd(&deg[d], 1);
}

// ---------- parallel scan, step 1: per-256-chunk sums ----------
__global__ void chunk_sum_kernel(const int* __restrict__ deg, int* __restrict__ psum, int n) {
  int c = blockIdx.x;
  int i = c * 256 + threadIdx.x;
  int lane = threadIdx.x & 63, wid = threadIdx.x >> 6;
  int v = (i < n) ? deg[i] : 0;
#pragma unroll
  for (int off = 32; off; off >>= 1) v += __shfl_xor(v, off);
  __shared__ int ws[4];
  if (lane == 0) ws[wid] = v;
  __syncthreads();
  if (threadIdx.x == 0) psum[c] = ws[0] + ws[1] + ws[2] + ws[3];
}

// ---------- block-wide inclusive scan helper (256 threads) ----------
__device__ __forceinline__ int block_incl_scan_256(int v) {
  int lane = threadIdx.x & 63, wid = threadIdx.x >> 6;
#pragma unroll
  for (int off = 1; off < 64; off <<= 1) {
    int t = __shfl_up(v, off);
    if (lane >= off) v += t;
  }
  __shared__ int wsum[4];
  if (lane == 63) wsum[wid] = v;
  __syncthreads();
  int add = 0;
  for (int w = 0; w < wid; ++w) add += wsum[w];
  return v + add;
}

// ---------- parallel scan, step 2: inclusive scan of chunk sums (nc <= 256) ----------
__global__ void scan_chunks_kernel(int* __restrict__ psum, int nc) {
  int i = threadIdx.x;
  int v = (i < nc) ? psum[i] : 0;
  int incl = block_incl_scan_256(v);
  if (i < nc) psum[i] = incl;
}

// ---------- parallel scan, step 3: intra-chunk scan + chunk offset -> rowptr ----------
__global__ void scan_final_kernel(const int* __restrict__ deg, const int* __restrict__ psum,
                                  int* __restrict__ rowptr, int n) {
  int c = blockIdx.x;
  int i = c * 256 + threadIdx.x;
  int v = (i < n) ? deg[i] : 0;
  int incl = block_incl_scan_256(v);
  int off = (c > 0) ? psum[c - 1] : 0;
  if (i < n) rowptr[i + 1] = off + incl;
  if (i == 0) rowptr[0] = 0;
}

// ---------- CSR build: fill src ids into dst buckets ----------
__global__ void fill_kernel(const int* __restrict__ ei, int* __restrict__ cnt,
                            const int* __restrict__ rowptr, int* __restrict__ ebuf,
                            int nE, int nN) {
  int t = blockIdx.x * blockDim.x + threadIdx.x;
  if (t >= nE + nN) return;
  int s, d;
  if (t < nE) { s = ei[t]; d = ei[nE + t]; } else { s = t - nE; d = s; }
  int pos = rowptr[d] + atomicAdd(&cnt[d], 1);
  ebuf[pos] = s;
}

// ---------- fused GATv2 layer: wave per dst, 4x16-lane edge groups ----------
// Round-13 structure (1 edge/group-iter, occupancy-bound optimum); XL gathered
// fp16. OutT=__half for both layers now (feeds MFMA GEMM / predict).
template<int H, typename OutT>
__global__ void gat_fused_kernel(const __half* __restrict__ XL, const float* __restrict__ XR,
                                 const int* __restrict__ rowptr, const int* __restrict__ ebuf,
                                 const float* __restrict__ att, const float* __restrict__ bias,
                                 OutT* __restrict__ out, int nN) {
  constexpr bool HAS2 = (H > 64);
  int lane = threadIdx.x & 63;
  int wid = threadIdx.x >> 6;
  int d = blockIdx.x * (blockDim.x >> 6) + wid;
  if (d >= nN) return;
  int g = lane >> 4;   // edge group 0..3
  int ll = lane & 15;  // lane within group
  const int cA = ll * 4;
  const int cB = 64 + ll * 2;

  const float* xrrow = XR + (size_t)d * H;
  float4 xr4 = *(const float4*)(xrrow + cA);
  float4 a4 = *(const float4*)(att + cA);
  float4 s4 = make_float4(a4.x * NEG_SLOPE, a4.y * NEG_SLOPE, a4.z * NEG_SLOPE, a4.w * NEG_SLOPE);
  float2 xr2 = make_float2(0.f, 0.f), a2 = make_float2(0.f, 0.f), s2 = make_float2(0.f, 0.f);
  if constexpr (HAS2) {
    xr2 = *(const float2*)(xrrow + cB);
    a2 = *(const float2*)(att + cB);
    s2 = make_float2(a2.x * NEG_SLOPE, a2.y * NEG_SLOPE);
  }

  float m = -1e30f, den = 0.f;
  float4 o4 = make_float4(0.f, 0.f, 0.f, 0.f);
  float2 o2 = make_float2(0.f, 0.f);

  int beg = rowptr[d], end = rowptr[d + 1];
  int i = beg + g;
  int s = (i < end) ? ebuf[i] : 0;
  while (i < end) {
    int inext = i + 4;
    int snext = (inext < end) ? ebuf[inext] : 0;
    const __half* R = XL + (size_t)s * H;
    uint2 ua = *(const uint2*)(R + cA);
    float2 fa0 = __half22float2(u2h2(ua.x));
    float2 fa1 = __half22float2(u2h2(ua.y));
    float4 x4 = make_float4(fa0.x, fa0.y, fa1.x, fa1.y);
    float2 x2 = make_float2(0.f, 0.f);
    if constexpr (HAS2) {
      unsigned ub = *(const unsigned*)(R + cB);
      x2 = __half22float2(u2h2(ub));
    }
    float f, p;
    f = x4.x + xr4.x; p = fmaf(fmaxf(f, 0.f), a4.x, fminf(f, 0.f) * s4.x);
    f = x4.y + xr4.y; p = fmaf(fmaxf(f, 0.f), a4.y, fmaf(fminf(f, 0.f), s4.y, p));
    f = x4.z + xr4.z; p = fmaf(fmaxf(f, 0.f), a4.z, fmaf(fminf(f, 0.f), s4.z, p));
    f = x4.w + xr4.w; p = fmaf(fmaxf(f, 0.f), a4.w, fmaf(fminf(f, 0.f), s4.w, p));
    if constexpr (HAS2) {
      f = x2.x + xr2.x; p = fmaf(fmaxf(f, 0.f), a2.x, fmaf(fminf(f, 0.f), s2.x, p));
      f = x2.y + xr2.y; p = fmaf(fmaxf(f, 0.f), a2.y, fmaf(fminf(f, 0.f), s2.y, p));
    }
    p += __shfl_xor(p, 1);
    p += __shfl_xor(p, 2);
    p += __shfl_xor(p, 4);
    p += __shfl_xor(p, 8);
    if (p > m) {
      float scl = __expf(m - p);
      den *= scl;
      o4.x *= scl; o4.y *= scl; o4.z *= scl; o4.w *= scl;
      if constexpr (HAS2) { o2.x *= scl; o2.y *= scl; }
      m = p;
    }
    float w = __expf(p - m);
    den += w;
    o4.x = fmaf(w, x4.x, o4.x); o4.y = fmaf(w, x4.y, o4.y);
    o4.z = fmaf(w, x4.z, o4.z); o4.w = fmaf(w, x4.w, o4.w);
    if constexpr (HAS2) { o2.x = fmaf(w, x2.x, o2.x); o2.y = fmaf(w, x2.y, o2.y); }
    i = inext;
    s = snext;
  }

  // merge the 4 groups (flash-style), xor 16 then xor 32
#pragma unroll
  for (int msk = 16; msk <= 32; msk <<= 1) {
    float m2 = __shfl_xor(m, msk);
    float den2 = __shfl_xor(den, msk);
    float q0 = __shfl_xor(o4.x, msk), q1 = __shfl_xor(o4.y, msk);
    float q2 = __shfl_xor(o4.z, msk), q3 = __shfl_xor(o4.w, msk);
    float q4 = 0.f, q5 = 0.f;
    if constexpr (HAS2) { q4 = __shfl_xor(o2.x, msk); q5 = __shfl_xor(o2.y, msk); }
    float M = fmaxf(m, m2);
    float sa = __expf(m - M), sb = __expf(m2 - M);
    den = den * sa + den2 * sb;
    o4.x = o4.x * sa + q0 * sb; o4.y = o4.y * sa + q1 * sb;
    o4.z = o4.z * sa + q2 * sb; o4.w = o4.w * sa + q3 * sb;
    if constexpr (HAS2) { o2.x = o2.x * sa + q4 * sb; o2.y = o2.y * sa + q5 * sb; }
    m = M;
  }

  if (g == 0) {
    float inv = 1.f / (den + 1e-16f);
    float4 b4 = *(const float4*)(bias + cA);
    float4 y;
    y.x = fmaf(o4.x, inv, b4.x); y.x = y.x > 0.f ? y.x : 0.f;
    y.y = fmaf(o4.y, inv, b4.y); y.y = y.y > 0.f ? y.y : 0.f;
    y.z = fmaf(o4.z, inv, b4.z); y.z = y.z > 0.f ? y.z : 0.f;
    y.w = fmaf(o4.w, inv, b4.w); y.w = y.w > 0.f ? y.w : 0.f;
    if constexpr (__hip_internal::is_same<OutT, float>::value) {
      *(float4*)(out + (size_t)d * H + cA) = y;
      if constexpr (HAS2) {
        float2 b2 = *(const float2*)(bias + cB);
        float2 z;
        z.x = fmaf(o2.x, inv, b2.x); z.x = z.x > 0.f ? z.x : 0.f;
        z.y = fmaf(o2.y, inv, b2.y); z.y = z.y > 0.f ? z.y : 0.f;
        *(float2*)(out + (size_t)d * H + cB) = z;
      }
    } else {
      uint2 uv;
      uv.x = h22u(__floats2half2_rn(y.x, y.y));
      uv.y = h22u(__floats2half2_rn(y.z, y.w));
      *(uint2*)((__half*)out + (size_t)d * H + cA) = uv;
      if constexpr (HAS2) {
        float2 b2 = *(const float2*)(bias + cB);
        float zx = fmaf(o2.x, inv, b2.x); zx = zx > 0.f ? zx : 0.f;
        float zy = fmaf(o2.y, inv, b2.y); zy = zy > 0.f ? zy : 0.f;
        *(unsigned*)((__half*)out + (size_t)d * H + cB) = h22u(__floats2half2_rn(zx, zy));
      }
    }
  }
}

// ---------- out[l] = sum_k hs[k]*hd[k]*(Wp[k,0]+Wp[k,1]) + bp0+bp1, fp16 h ----------
__global__ void predict_kernel(const __half* __restrict__ h, const int* __restrict__ eli,
                               const float* __restrict__ Wp, const float* __restrict__ bp,
                               float* __restrict__ out, int L) {
  int l = blockIdx.x * blockDim.x + threadIdx.x;
  if (l >= L) return;
  int s = eli[l], d = eli[L + l];
  const uint4* a4 = (const uint4*)(h + (size_t)s * 64);
  const uint4* b4 = (const uint4*)(h + (size_t)d * 64);
  const float4* wp4 = (const float4*)Wp;
  float acc = bp[0] + bp[1];
#pragma unroll
  for (int i = 0; i < 8; ++i) {
    uint4 ua = a4[i], ub = b4[i];
    float2 u0 = __half22float2(u2h2(ua.x)), v0 = __half22float2(u2h2(ub.x));
    float2 u1 = __half22float2(u2h2(ua.y)), v1 = __half22float2(u2h2(ub.y));
    float2 u2_ = __half22float2(u2h2(ua.z)), v2 = __half22float2(u2h2(ub.z));
    float2 u3 = __half22float2(u2h2(ua.w)), v3 = __half22float2(u2h2(ub.w));
    float4 w0 = wp4[4 * i + 0];
    float4 w1 = wp4[4 * i + 1];
    float4 w2 = wp4[4 * i + 2];
    float4 w3 = wp4[4 * i + 3];
    acc = fmaf(u0.x * v0.x, w0.x + w0.y, acc);
    acc = fmaf(u0.y * v0.y, w0.z + w0.w, acc);
    acc = fmaf(u1.x * v1.x, w1.x + w1.y, acc);
    acc = fmaf(u1.y * v1.y, w1.z + w1.w, acc);
    acc = fmaf(u2_.x * v2.x, w2.x + w2.y, acc);
    acc = fmaf(u2_.y * v2.y, w2.z + w2.w, acc);
    acc = fmaf(u3.x * v3.x, w3.x + w3.y, acc);
    acc = fmaf(u3.y * v3.y, w3.z + w3.w, acc);
  }
  out[l] = acc;
}

static inline int cdiv(long long a, int b) { return (int)((a + b - 1) / b); }

extern "C" void kernel_launch(void* const* d_in, const int* in_sizes, int n_in,
                              void* d_out, int out_size, void* d_ws, size_t ws_size,
                              hipStream_t stream) {
  const float* x    = (const float*)d_in[0];
  const int*   ei   = (const int*)d_in[1];
  const int*   eli  = (const int*)d_in[2];
  const float* Wl1  = (const float*)d_in[3];
  const float* Wr1  = (const float*)d_in[4];
  const float* att1 = (const float*)d_in[5];
  const float* b1   = (const float*)d_in[6];
  const float* Wl2  = (const float*)d_in[7];
  const float* Wr2  = (const float*)d_in[8];
  const float* att2 = (const float*)d_in[9];
  const float* b2   = (const float*)d_in[10];
  const float* Wp   = (const float*)d_in[11];
  const float* bp   = (const float*)d_in[12];
  float* out = (float*)d_out;

  const int N = in_sizes[0] / 128;
  const int E = in_sizes[1] / 2;
  const int L = in_sizes[2] / 2;
  const int T = E + N;
  const int NC = cdiv(N, 256);

  // workspace layout (all 16B-aligned given N*sizes divisible by 16)
  _Float16* xh = (_Float16*)d_ws;                       // [N*128] fp16 x
  __half* xlh  = (__half*)(xh + (size_t)N * 128);       // [N*96] gather table (L1:96, L2:64)
  float* xr    = (float*)(xlh + (size_t)N * 96);        // [N*96] fp32 xr
  __half* h1h  = (__half*)(xr + (size_t)N * 96);        // [N*96] fp16 h1 (L2 GEMM input)
  __half* h2h  = h1h + (size_t)N * 96;                  // [N*64] fp16 h2 (predict input)
  int* deg     = (int*)(h2h + (size_t)N * 64);          // [N]
  int* cnt     = deg + N;                               // [N]
  int* rowptr  = cnt + N;                               // [N+1]
  int* ebuf    = rowptr + N + 1;                        // [T]
  int* psum    = ebuf + T;                              // [NC]

  const int BS = 256;
  const int GB64 = cdiv(N, 64);  // MFMA GEMM blocks (64 rows/block)

  // ---------------- CSR build (once, shared by both layers) ----------------
  (void)hipMemsetAsync(deg, 0, (size_t)(2 * N) * 4, stream);  // deg + cnt
  hist_kernel<<<cdiv(T, BS), BS, 0, stream>>>(ei, deg, E, N);
  chunk_sum_kernel<<<NC, 256, 0, stream>>>(deg, psum, N);
  scan_chunks_kernel<<<1, 256, 0, stream>>>(psum, NC);
  scan_final_kernel<<<NC, 256, 0, stream>>>(deg, psum, rowptr, N);
  fill_kernel<<<cdiv(T, BS), BS, 0, stream>>>(ei, cnt, rowptr, ebuf, E, N);

  // ---------------- x -> fp16 ----------------
  cvt_f2h_kernel<<<cdiv((long long)N * 128 / 4, BS), BS, 0, stream>>>(x, xh, N * 32);

  // ---------------- layer 1 (128 -> 96), MFMA ----------------
  gemm2_mfma_kernel<128, 96><<<GB64, 256, 0, stream>>>(xh, Wl1, Wr1, xlh, xr, N);
  gat_fused_kernel<96, __half><<<cdiv(N, BS / 64), BS, 0, stream>>>(xlh, xr, rowptr, ebuf, att1, b1, h1h, N);

  // ---------------- layer 2 (96 -> 64), MFMA ----------------
  gemm2_mfma_kernel<96, 64><<<GB64, 256, 0, stream>>>((const _Float16*)h1h, Wl2, Wr2, xlh, xr, N);
  gat_fused_kernel<64, __half><<<cdiv(N, BS / 64), BS, 0, stream>>>(xlh, xr, rowptr, ebuf, att2, b2, h2h, N);

  // ---------------- link predictor ----------------
  predict_kernel<<<cdiv(L, BS), BS, 0, stream>>>(h2h, eli, Wp, bp, out, L);
}

// Round 19
// 241.425 us; speedup vs baseline: 1.1817x; 1.1817x over previous
//
#include <hip/hip_runtime.h>
#include <hip/hip_fp16.h>

#define NEG_SLOPE 0.2f

typedef _Float16 half8_t __attribute__((ext_vector_type(8)));
typedef _Float16 half4_t __attribute__((ext_vector_type(4)));
typedef float f32x4 __attribute__((ext_vector_type(4)));

__device__ __forceinline__ __half2 u2h2(unsigned u) {
  union { unsigned u; __half2 h; } cv; cv.u = u; return cv.h;
}
__device__ __forceinline__ unsigned h22u(__half2 h) {
  union { unsigned u; __half2 h; } cv; cv.h = h; return cv.u;
}

// ---------- x (f32) -> fp16 table, float4-vectorized ----------
__global__ void cvt_f2h_kernel(const float* __restrict__ in, _Float16* __restrict__ out, int n4) {
  int i = blockIdx.x * blockDim.x + threadIdx.x;
  if (i >= n4) return;
  float4 v = ((const float4*)in)[i];
  half4_t h = { (_Float16)v.x, (_Float16)v.y, (_Float16)v.z, (_Float16)v.w };
  ((half4_t*)out)[i] = h;
}

// ---------- one-shot W transpose: W[K][H] f32 -> Wt[H][K+4] fp16 (pad never read) ----------
template<int K, int H>
__global__ void wtrans_kernel(const float* __restrict__ W, _Float16* __restrict__ Wt) {
  int idx = blockIdx.x * blockDim.x + threadIdx.x;
  if (idx >= K * H) return;
  int k = idx / H, h = idx - k * H;  // consecutive idx -> consecutive h: coalesced read
  Wt[h * (K + 4) + k] = (_Float16)W[idx];
}

// ---------- dual-output MFMA GEMM (fp16 in, f32 acc): Y1(fp16)=X@W1, Y2(f32)=X@W2 ----------
// W pre-transposed fp16 [H][K+4] in global: LDS staging is a coalesced uint4 memcpy.
// 4 waves/block, wave = 16 rows x H cols via mfma_f32_16x16x32_f16.
// Fragment maps (VERIFIED round 18, absmax == vector version):
//   A: row=lane&15, k = kt*32 + (lane>>4)*4 + (j&3) + (j>>2)*16
//   C/D: col=lane&15, row=(lane>>4)*4+j
template<int K, int H>
__global__ __launch_bounds__(256) void gemm2_mfma_kernel(const _Float16* __restrict__ Xh,
                                                         const _Float16* __restrict__ Wt1,
                                                         const _Float16* __restrict__ Wt2,
                                                         __half* __restrict__ Y1,
                                                         float* __restrict__ Y2, int n) {
  constexpr int KP = K + 4;       // padded stride (halves) -> 16-lane B reads hit distinct banks
  constexpr int KT = K / 32;      // MFMA K-steps
  constexpr int CT = H / 16;      // col tiles
  constexpr int WB = H * KP;      // halves per table (L1: 12672, L2: 6400 — both %8==0)
  __shared__ _Float16 Ws1[WB];
  __shared__ _Float16 Ws2[WB];
  const int tid = threadIdx.x;
  for (int i = tid; i < WB / 8; i += 256) {
    ((uint4*)Ws1)[i] = ((const uint4*)Wt1)[i];
    ((uint4*)Ws2)[i] = ((const uint4*)Wt2)[i];
  }
  __syncthreads();
  const int wv = tid >> 6, lane = tid & 63;
  const int q = lane >> 4, c = lane & 15;
  const int r0 = blockIdx.x * 64 + wv * 16;
  if (r0 >= n) return;
  int arow = r0 + c; if (arow >= n) arow = n - 1;
  const _Float16* Xrow = Xh + (size_t)arow * K;
  half8_t A[KT];
#pragma unroll
  for (int kt = 0; kt < KT; ++kt) {
    half4_t lo = *(const half4_t*)(Xrow + kt * 32 + q * 4);
    half4_t hi = *(const half4_t*)(Xrow + kt * 32 + 16 + q * 4);
    A[kt] = __builtin_shufflevector(lo, hi, 0, 1, 2, 3, 4, 5, 6, 7);
  }
#pragma unroll
  for (int ct = 0; ct < CT; ++ct) {
    const int col = ct * 16 + c;
    f32x4 acc1 = {0.f, 0.f, 0.f, 0.f};
    f32x4 acc2 = {0.f, 0.f, 0.f, 0.f};
#pragma unroll
    for (int kt = 0; kt < KT; ++kt) {
      const _Float16* w1p = &Ws1[col * KP + kt * 32 + q * 4];
      const _Float16* w2p = &Ws2[col * KP + kt * 32 + q * 4];
      half4_t b1lo = *(const half4_t*)w1p;
      half4_t b1hi = *(const half4_t*)(w1p + 16);
      half4_t b2lo = *(const half4_t*)w2p;
      half4_t b2hi = *(const half4_t*)(w2p + 16);
      half8_t B1 = __builtin_shufflevector(b1lo, b1hi, 0, 1, 2, 3, 4, 5, 6, 7);
      half8_t B2 = __builtin_shufflevector(b2lo, b2hi, 0, 1, 2, 3, 4, 5, 6, 7);
      acc1 = __builtin_amdgcn_mfma_f32_16x16x32_f16(A[kt], B1, acc1, 0, 0, 0);
      acc2 = __builtin_amdgcn_mfma_f32_16x16x32_f16(A[kt], B2, acc2, 0, 0, 0);
    }
#pragma unroll
    for (int j = 0; j < 4; ++j) {
      int rowg = r0 + q * 4 + j;
      if (rowg < n) {
        Y1[(size_t)rowg * H + col] = __float2half(acc1[j]);
        Y2[(size_t)rowg * H + col] = acc2[j];
      }
    }
  }
}

// ---------- CSR build: histogram of dst ----------
__global__ void hist_kernel(const int* __restrict__ ei, int* __restrict__ deg, int nE, int nN) {
  int t = blockIdx.x * blockDim.x + threadIdx.x;
  if (t >= nE + nN) return;
  int d = (t < nE) ? ei[nE + t] : (t - nE);
  atomicAdd(&deg[d], 1);
}

// ---------- parallel scan, step 1: per-256-chunk sums ----------
__global__ void chunk_sum_kernel(const int* __restrict__ deg, int* __restrict__ psum, int n) {
  int c = blockIdx.x;
  int i = c * 256 + threadIdx.x;
  int lane = threadIdx.x & 63, wid = threadIdx.x >> 6;
  int v = (i < n) ? deg[i] : 0;
#pragma unroll
  for (int off = 32; off; off >>= 1) v += __shfl_xor(v, off);
  __shared__ int ws[4];
  if (lane == 0) ws[wid] = v;
  __syncthreads();
  if (threadIdx.x == 0) psum[c] = ws[0] + ws[1] + ws[2] + ws[3];
}

// ---------- block-wide inclusive scan helper (256 threads) ----------
__device__ __forceinline__ int block_incl_scan_256(int v) {
  int lane = threadIdx.x & 63, wid = threadIdx.x >> 6;
#pragma unroll
  for (int off = 1; off < 64; off <<= 1) {
    int t = __shfl_up(v, off);
    if (lane >= off) v += t;
  }
  __shared__ int wsum[4];
  if (lane == 63) wsum[wid] = v;
  __syncthreads();
  int add = 0;
  for (int w = 0; w < wid; ++w) add += wsum[w];
  return v + add;
}

// ---------- parallel scan, step 2: inclusive scan of chunk sums (nc <= 256) ----------
__global__ void scan_chunks_kernel(int* __restrict__ psum, int nc) {
  int i = threadIdx.x;
  int v = (i < nc) ? psum[i] : 0;
  int incl = block_incl_scan_256(v);
  if (i < nc) psum[i] = incl;
}

// ---------- parallel scan, step 3: intra-chunk scan + chunk offset -> rowptr ----------
__global__ void scan_final_kernel(const int* __restrict__ deg, const int* __restrict__ psum,
                                  int* __restrict__ rowptr, int n) {
  int c = blockIdx.x;
  int i = c * 256 + threadIdx.x;
  int v = (i < n) ? deg[i] : 0;
  int incl = block_incl_scan_256(v);
  int off = (c > 0) ? psum[c - 1] : 0;
  if (i < n) rowptr[i + 1] = off + incl;
  if (i == 0) rowptr[0] = 0;
}

// ---------- CSR build: fill src ids into dst buckets ----------
__global__ void fill_kernel(const int* __restrict__ ei, int* __restrict__ cnt,
                            const int* __restrict__ rowptr, int* __restrict__ ebuf,
                            int nE, int nN) {
  int t = blockIdx.x * blockDim.x + threadIdx.x;
  if (t >= nE + nN) return;
  int s, d;
  if (t < nE) { s = ei[t]; d = ei[nE + t]; } else { s = t - nE; d = s; }
  int pos = rowptr[d] + atomicAdd(&cnt[d], 1);
  ebuf[pos] = s;
}

// ---------- fused GATv2 layer: wave per dst, 4x16-lane edge groups ----------
template<int H, typename OutT>
__global__ void gat_fused_kernel(const __half* __restrict__ XL, const float* __restrict__ XR,
                                 const int* __restrict__ rowptr, const int* __restrict__ ebuf,
                                 const float* __restrict__ att, const float* __restrict__ bias,
                                 OutT* __restrict__ out, int nN) {
  constexpr bool HAS2 = (H > 64);
  int lane = threadIdx.x & 63;
  int wid = threadIdx.x >> 6;
  int d = blockIdx.x * (blockDim.x >> 6) + wid;
  if (d >= nN) return;
  int g = lane >> 4;   // edge group 0..3
  int ll = lane & 15;  // lane within group
  const int cA = ll * 4;
  const int cB = 64 + ll * 2;

  const float* xrrow = XR + (size_t)d * H;
  float4 xr4 = *(const float4*)(xrrow + cA);
  float4 a4 = *(const float4*)(att + cA);
  float4 s4 = make_float4(a4.x * NEG_SLOPE, a4.y * NEG_SLOPE, a4.z * NEG_SLOPE, a4.w * NEG_SLOPE);
  float2 xr2 = make_float2(0.f, 0.f), a2 = make_float2(0.f, 0.f), s2 = make_float2(0.f, 0.f);
  if constexpr (HAS2) {
    xr2 = *(const float2*)(xrrow + cB);
    a2 = *(const float2*)(att + cB);
    s2 = make_float2(a2.x * NEG_SLOPE, a2.y * NEG_SLOPE);
  }

  float m = -1e30f, den = 0.f;
  float4 o4 = make_float4(0.f, 0.f, 0.f, 0.f);
  float2 o2 = make_float2(0.f, 0.f);

  int beg = rowptr[d], end = rowptr[d + 1];
  int i = beg + g;
  int s = (i < end) ? ebuf[i] : 0;
  while (i < end) {
    int inext = i + 4;
    int snext = (inext < end) ? ebuf[inext] : 0;
    const __half* R = XL + (size_t)s * H;
    uint2 ua = *(const uint2*)(R + cA);
    float2 fa0 = __half22float2(u2h2(ua.x));
    float2 fa1 = __half22float2(u2h2(ua.y));
    float4 x4 = make_float4(fa0.x, fa0.y, fa1.x, fa1.y);
    float2 x2 = make_float2(0.f, 0.f);
    if constexpr (HAS2) {
      unsigned ub = *(const unsigned*)(R + cB);
      x2 = __half22float2(u2h2(ub));
    }
    float f, p;
    f = x4.x + xr4.x; p = fmaf(fmaxf(f, 0.f), a4.x, fminf(f, 0.f) * s4.x);
    f = x4.y + xr4.y; p = fmaf(fmaxf(f, 0.f), a4.y, fmaf(fminf(f, 0.f), s4.y, p));
    f = x4.z + xr4.z; p = fmaf(fmaxf(f, 0.f), a4.z, fmaf(fminf(f, 0.f), s4.z, p));
    f = x4.w + xr4.w; p = fmaf(fmaxf(f, 0.f), a4.w, fmaf(fminf(f, 0.f), s4.w, p));
    if constexpr (HAS2) {
      f = x2.x + xr2.x; p = fmaf(fmaxf(f, 0.f), a2.x, fmaf(fminf(f, 0.f), s2.x, p));
      f = x2.y + xr2.y; p = fmaf(fmaxf(f, 0.f), a2.y, fmaf(fminf(f, 0.f), s2.y, p));
    }
    p += __shfl_xor(p, 1);
    p += __shfl_xor(p, 2);
    p += __shfl_xor(p, 4);
    p += __shfl_xor(p, 8);
    if (p > m) {
      float scl = __expf(m - p);
      den *= scl;
      o4.x *= scl; o4.y *= scl; o4.z *= scl; o4.w *= scl;
      if constexpr (HAS2) { o2.x *= scl; o2.y *= scl; }
      m = p;
    }
    float w = __expf(p - m);
    den += w;
    o4.x = fmaf(w, x4.x, o4.x); o4.y = fmaf(w, x4.y, o4.y);
    o4.z = fmaf(w, x4.z, o4.z); o4.w = fmaf(w, x4.w, o4.w);
    if constexpr (HAS2) { o2.x = fmaf(w, x2.x, o2.x); o2.y = fmaf(w, x2.y, o2.y); }
    i = inext;
    s = snext;
  }

#pragma unroll
  for (int msk = 16; msk <= 32; msk <<= 1) {
    float m2 = __shfl_xor(m, msk);
    float den2 = __shfl_xor(den, msk);
    float q0 = __shfl_xor(o4.x, msk), q1 = __shfl_xor(o4.y, msk);
    float q2 = __shfl_xor(o4.z, msk), q3 = __shfl_xor(o4.w, msk);
    float q4 = 0.f, q5 = 0.f;
    if constexpr (HAS2) { q4 = __shfl_xor(o2.x, msk); q5 = __shfl_xor(o2.y, msk); }
    float M = fmaxf(m, m2);
    float sa = __expf(m - M), sb = __expf(m2 - M);
    den = den * sa + den2 * sb;
    o4.x = o4.x * sa + q0 * sb; o4.y = o4.y * sa + q1 * sb;
    o4.z = o4.z * sa + q2 * sb; o4.w = o4.w * sa + q3 * sb;
    if constexpr (HAS2) { o2.x = o2.x * sa + q4 * sb; o2.y = o2.y * sa + q5 * sb; }
    m = M;
  }

  if (g == 0) {
    float inv = 1.f / (den + 1e-16f);
    float4 b4 = *(const float4*)(bias + cA);
    float4 y;
    y.x = fmaf(o4.x, inv, b4.x); y.x = y.x > 0.f ? y.x : 0.f;
    y.y = fmaf(o4.y, inv, b4.y); y.y = y.y > 0.f ? y.y : 0.f;
    y.z = fmaf(o4.z, inv, b4.z); y.z = y.z > 0.f ? y.z : 0.f;
    y.w = fmaf(o4.w, inv, b4.w); y.w = y.w > 0.f ? y.w : 0.f;
    if constexpr (__hip_internal::is_same<OutT, float>::value) {
      *(float4*)(out + (size_t)d * H + cA) = y;
      if constexpr (HAS2) {
        float2 b2 = *(const float2*)(bias + cB);
        float2 z;
        z.x = fmaf(o2.x, inv, b2.x); z.x = z.x > 0.f ? z.x : 0.f;
        z.y = fmaf(o2.y, inv, b2.y); z.y = z.y > 0.f ? z.y : 0.f;
        *(float2*)(out + (size_t)d * H + cB) = z;
      }
    } else {
      uint2 uv;
      uv.x = h22u(__floats2half2_rn(y.x, y.y));
      uv.y = h22u(__floats2half2_rn(y.z, y.w));
      *(uint2*)((__half*)out + (size_t)d * H + cA) = uv;
      if constexpr (HAS2) {
        float2 b2 = *(const float2*)(bias + cB);
        float zx = fmaf(o2.x, inv, b2.x); zx = zx > 0.f ? zx : 0.f;
        float zy = fmaf(o2.y, inv, b2.y); zy = zy > 0.f ? zy : 0.f;
        *(unsigned*)((__half*)out + (size_t)d * H + cB) = h22u(__floats2half2_rn(zx, zy));
      }
    }
  }
}

// ---------- out[l] = sum_k hs[k]*hd[k]*(Wp[k,0]+Wp[k,1]) + bp0+bp1, fp16 h ----------
__global__ void predict_kernel(const __half* __restrict__ h, const int* __restrict__ eli,
                               const float* __restrict__ Wp, const float* __restrict__ bp,
                               float* __restrict__ out, int L) {
  int l = blockIdx.x * blockDim.x + threadIdx.x;
  if (l >= L) return;
  int s = eli[l], d = eli[L + l];
  const uint4* a4 = (const uint4*)(h + (size_t)s * 64);
  const uint4* b4 = (const uint4*)(h + (size_t)d * 64);
  const float4* wp4 = (const float4*)Wp;
  float acc = bp[0] + bp[1];
#pragma unroll
  for (int i = 0; i < 8; ++i) {
    uint4 ua = a4[i], ub = b4[i];
    float2 u0 = __half22float2(u2h2(ua.x)), v0 = __half22float2(u2h2(ub.x));
    float2 u1 = __half22float2(u2h2(ua.y)), v1 = __half22float2(u2h2(ub.y));
    float2 u2_ = __half22float2(u2h2(ua.z)), v2 = __half22float2(u2h2(ub.z));
    float2 u3 = __half22float2(u2h2(ua.w)), v3 = __half22float2(u2h2(ub.w));
    float4 w0 = wp4[4 * i + 0];
    float4 w1 = wp4[4 * i + 1];
    float4 w2 = wp4[4 * i + 2];
    float4 w3 = wp4[4 * i + 3];
    acc = fmaf(u0.x * v0.x, w0.x + w0.y, acc);
    acc = fmaf(u0.y * v0.y, w0.z + w0.w, acc);
    acc = fmaf(u1.x * v1.x, w1.x + w1.y, acc);
    acc = fmaf(u1.y * v1.y, w1.z + w1.w, acc);
    acc = fmaf(u2_.x * v2.x, w2.x + w2.y, acc);
    acc = fmaf(u2_.y * v2.y, w2.z + w2.w, acc);
    acc = fmaf(u3.x * v3.x, w3.x + w3.y, acc);
    acc = fmaf(u3.y * v3.y, w3.z + w3.w, acc);
  }
  out[l] = acc;
}

static inline int cdiv(long long a, int b) { return (int)((a + b - 1) / b); }

extern "C" void kernel_launch(void* const* d_in, const int* in_sizes, int n_in,
                              void* d_out, int out_size, void* d_ws, size_t ws_size,
                              hipStream_t stream) {
  const float* x    = (const float*)d_in[0];
  const int*   ei   = (const int*)d_in[1];
  const int*   eli  = (const int*)d_in[2];
  const float* Wl1  = (const float*)d_in[3];
  const float* Wr1  = (const float*)d_in[4];
  const float* att1 = (const float*)d_in[5];
  const float* b1   = (const float*)d_in[6];
  const float* Wl2  = (const float*)d_in[7];
  const float* Wr2  = (const float*)d_in[8];
  const float* att2 = (const float*)d_in[9];
  const float* b2   = (const float*)d_in[10];
  const float* Wp   = (const float*)d_in[11];
  const float* bp   = (const float*)d_in[12];
  float* out = (float*)d_out;

  const int N = in_sizes[0] / 128;
  const int E = in_sizes[1] / 2;
  const int L = in_sizes[2] / 2;
  const int T = E + N;
  const int NC = cdiv(N, 256);

  // workspace layout (all 16B-aligned)
  _Float16* xh   = (_Float16*)d_ws;                     // [N*128] fp16 x
  __half* xlh    = (__half*)(xh + (size_t)N * 128);     // [N*96] gather table
  float* xr      = (float*)(xlh + (size_t)N * 96);      // [N*96] fp32 xr
  __half* h1h    = (__half*)(xr + (size_t)N * 96);      // [N*96] fp16 h1
  __half* h2h    = h1h + (size_t)N * 96;                // [N*64] fp16 h2
  _Float16* wt1a = (_Float16*)(h2h + (size_t)N * 64);   // [96*132] Wl1^T fp16
  _Float16* wt1b = wt1a + 96 * 132;                     // [96*132] Wr1^T fp16
  _Float16* wt2a = wt1b + 96 * 132;                     // [64*100] Wl2^T fp16
  _Float16* wt2b = wt2a + 64 * 100;                     // [64*100] Wr2^T fp16
  int* deg       = (int*)(wt2b + 64 * 100);             // [N]
  int* cnt       = deg + N;                             // [N]
  int* rowptr    = cnt + N;                             // [N+1]
  int* ebuf      = rowptr + N + 1;                      // [T]
  int* psum      = ebuf + T;                            // [NC]

  const int BS = 256;
  const int GB64 = cdiv(N, 64);

  // ---------------- CSR build + one-shot converts ----------------
  (void)hipMemsetAsync(deg, 0, (size_t)(2 * N) * 4, stream);  // deg + cnt
  hist_kernel<<<cdiv(T, BS), BS, 0, stream>>>(ei, deg, E, N);
  chunk_sum_kernel<<<NC, 256, 0, stream>>>(deg, psum, N);
  scan_chunks_kernel<<<1, 256, 0, stream>>>(psum, NC);
  scan_final_kernel<<<NC, 256, 0, stream>>>(deg, psum, rowptr, N);
  fill_kernel<<<cdiv(T, BS), BS, 0, stream>>>(ei, cnt, rowptr, ebuf, E, N);

  cvt_f2h_kernel<<<cdiv((long long)N * 32, BS), BS, 0, stream>>>(x, xh, N * 32);
  wtrans_kernel<128, 96><<<cdiv(128 * 96, BS), BS, 0, stream>>>(Wl1, wt1a);
  wtrans_kernel<128, 96><<<cdiv(128 * 96, BS), BS, 0, stream>>>(Wr1, wt1b);
  wtrans_kernel<96, 64><<<cdiv(96 * 64, BS), BS, 0, stream>>>(Wl2, wt2a);
  wtrans_kernel<96, 64><<<cdiv(96 * 64, BS), BS, 0, stream>>>(Wr2, wt2b);

  // ---------------- layer 1 (128 -> 96), MFMA ----------------
  gemm2_mfma_kernel<128, 96><<<GB64, 256, 0, stream>>>(xh, wt1a, wt1b, xlh, xr, N);
  gat_fused_kernel<96, __half><<<cdiv(N, BS / 64), BS, 0, stream>>>(xlh, xr, rowptr, ebuf, att1, b1, h1h, N);

  // ---------------- layer 2 (96 -> 64), MFMA ----------------
  gemm2_mfma_kernel<96, 64><<<GB64, 256, 0, stream>>>((const _Float16*)h1h, wt2a, wt2b, xlh, xr, N);
  gat_fused_kernel<64, __half><<<cdiv(N, BS / 64), BS, 0, stream>>>(xlh, xr, rowptr, ebuf, att2, b2, h2h, N);

  // ---------------- link predictor ----------------
  predict_kernel<<<cdiv(L, BS), BS, 0, stream>>>(h2h, eli, Wp, bp, out, L);
}

// Round 20
// 222.498 us; speedup vs baseline: 1.2823x; 1.0851x over previous
//
#include <hip/hip_runtime.h>
#include <hip/hip_fp16.h>

#define NEG_SLOPE 0.2f

typedef _Float16 half8_t __attribute__((ext_vector_type(8)));
typedef _Float16 half4_t __attribute__((ext_vector_type(4)));
typedef float f32x4 __attribute__((ext_vector_type(4)));

__device__ __forceinline__ __half2 u2h2(unsigned u) {
  union { unsigned u; __half2 h; } cv; cv.u = u; return cv.h;
}
__device__ __forceinline__ unsigned h22u(__half2 h) {
  union { unsigned u; __half2 h; } cv; cv.h = h; return cv.u;
}

// ---------- fused prep: hist + x->fp16 + 4x W-transpose (6 launches -> 1) ----------
// Block ranges: [0,nbHist) hist; [nbHist,nbHist+nbCvt) cvt; rest: wtrans x4.
__global__ void prep_kernel(const int* __restrict__ ei, int* __restrict__ deg, int nE, int nN,
                            const float* __restrict__ x, _Float16* __restrict__ xh, int n4,
                            const float* __restrict__ Wl1, const float* __restrict__ Wr1,
                            _Float16* __restrict__ wt1a, _Float16* __restrict__ wt1b,
                            const float* __restrict__ Wl2, const float* __restrict__ Wr2,
                            _Float16* __restrict__ wt2a, _Float16* __restrict__ wt2b,
                            int nbHist, int nbCvt) {
  int b = blockIdx.x;
  if (b < nbHist) {
    int t = b * 256 + threadIdx.x;
    if (t < nE + nN) {
      int d = (t < nE) ? ei[nE + t] : (t - nE);
      atomicAdd(&deg[d], 1);
    }
  } else if (b < nbHist + nbCvt) {
    int i = (b - nbHist) * 256 + threadIdx.x;
    if (i < n4) {
      float4 v = ((const float4*)x)[i];
      half4_t h = { (_Float16)v.x, (_Float16)v.y, (_Float16)v.z, (_Float16)v.w };
      ((half4_t*)xh)[i] = h;
    }
  } else {
    constexpr int SZ1 = 128 * 96, SZ2 = 96 * 64;
    int idx = (b - nbHist - nbCvt) * 256 + threadIdx.x;
    if (idx < SZ1) {
      int k = idx / 96, h = idx - k * 96;
      wt1a[h * 132 + k] = (_Float16)Wl1[idx];
    } else if (idx < 2 * SZ1) {
      int j = idx - SZ1; int k = j / 96, h = j - k * 96;
      wt1b[h * 132 + k] = (_Float16)Wr1[j];
    } else if (idx < 2 * SZ1 + SZ2) {
      int j = idx - 2 * SZ1; int k = j / 64, h = j - k * 64;
      wt2a[h * 100 + k] = (_Float16)Wl2[j];
    } else if (idx < 2 * SZ1 + 2 * SZ2) {
      int j = idx - 2 * SZ1 - SZ2; int k = j / 64, h = j - k * 64;
      wt2b[h * 100 + k] = (_Float16)Wr2[j];
    }
  }
}

// ---------- dual-output MFMA GEMM (fp16 in, f32 acc): Y1(fp16)=X@W1, Y2(f32)=X@W2 ----------
// W pre-transposed fp16 [H][K+4] in global: LDS staging is a coalesced uint4 memcpy.
// Fragment maps (VERIFIED rounds 18/19): A row=lane&15, k=kt*32+(lane>>4)*4+(j&3)+(j>>2)*16;
// C/D col=lane&15, row=(lane>>4)*4+j.
template<int K, int H>
__global__ __launch_bounds__(256) void gemm2_mfma_kernel(const _Float16* __restrict__ Xh,
                                                         const _Float16* __restrict__ Wt1,
                                                         const _Float16* __restrict__ Wt2,
                                                         __half* __restrict__ Y1,
                                                         float* __restrict__ Y2, int n) {
  constexpr int KP = K + 4;
  constexpr int KT = K / 32;
  constexpr int CT = H / 16;
  constexpr int WB = H * KP;
  __shared__ _Float16 Ws1[WB];
  __shared__ _Float16 Ws2[WB];
  const int tid = threadIdx.x;
  for (int i = tid; i < WB / 8; i += 256) {
    ((uint4*)Ws1)[i] = ((const uint4*)Wt1)[i];
    ((uint4*)Ws2)[i] = ((const uint4*)Wt2)[i];
  }
  __syncthreads();
  const int wv = tid >> 6, lane = tid & 63;
  const int q = lane >> 4, c = lane & 15;
  const int r0 = blockIdx.x * 64 + wv * 16;
  if (r0 >= n) return;
  int arow = r0 + c; if (arow >= n) arow = n - 1;
  const _Float16* Xrow = Xh + (size_t)arow * K;
  half8_t A[KT];
#pragma unroll
  for (int kt = 0; kt < KT; ++kt) {
    half4_t lo = *(const half4_t*)(Xrow + kt * 32 + q * 4);
    half4_t hi = *(const half4_t*)(Xrow + kt * 32 + 16 + q * 4);
    A[kt] = __builtin_shufflevector(lo, hi, 0, 1, 2, 3, 4, 5, 6, 7);
  }
#pragma unroll
  for (int ct = 0; ct < CT; ++ct) {
    const int col = ct * 16 + c;
    f32x4 acc1 = {0.f, 0.f, 0.f, 0.f};
    f32x4 acc2 = {0.f, 0.f, 0.f, 0.f};
#pragma unroll
    for (int kt = 0; kt < KT; ++kt) {
      const _Float16* w1p = &Ws1[col * KP + kt * 32 + q * 4];
      const _Float16* w2p = &Ws2[col * KP + kt * 32 + q * 4];
      half4_t b1lo = *(const half4_t*)w1p;
      half4_t b1hi = *(const half4_t*)(w1p + 16);
      half4_t b2lo = *(const half4_t*)w2p;
      half4_t b2hi = *(const half4_t*)(w2p + 16);
      half8_t B1 = __builtin_shufflevector(b1lo, b1hi, 0, 1, 2, 3, 4, 5, 6, 7);
      half8_t B2 = __builtin_shufflevector(b2lo, b2hi, 0, 1, 2, 3, 4, 5, 6, 7);
      acc1 = __builtin_amdgcn_mfma_f32_16x16x32_f16(A[kt], B1, acc1, 0, 0, 0);
      acc2 = __builtin_amdgcn_mfma_f32_16x16x32_f16(A[kt], B2, acc2, 0, 0, 0);
    }
#pragma unroll
    for (int j = 0; j < 4; ++j) {
      int rowg = r0 + q * 4 + j;
      if (rowg < n) {
        Y1[(size_t)rowg * H + col] = __float2half(acc1[j]);
        Y2[(size_t)rowg * H + col] = acc2[j];
      }
    }
  }
}

// ---------- parallel scan, step 1: per-256-chunk sums ----------
__global__ void chunk_sum_kernel(const int* __restrict__ deg, int* __restrict__ psum, int n) {
  int c = blockIdx.x;
  int i = c * 256 + threadIdx.x;
  int lane = threadIdx.x & 63, wid = threadIdx.x >> 6;
  int v = (i < n) ? deg[i] : 0;
#pragma unroll
  for (int off = 32; off; off >>= 1) v += __shfl_xor(v, off);
  __shared__ int ws[4];
  if (lane == 0) ws[wid] = v;
  __syncthreads();
  if (threadIdx.x == 0) psum[c] = ws[0] + ws[1] + ws[2] + ws[3];
}

// ---------- block-wide inclusive scan helper (256 threads) ----------
__device__ __forceinline__ int block_incl_scan_256(int v) {
  int lane = threadIdx.x & 63, wid = threadIdx.x >> 6;
#pragma unroll
  for (int off = 1; off < 64; off <<= 1) {
    int t = __shfl_up(v, off);
    if (lane >= off) v += t;
  }
  __shared__ int wsum[4];
  if (lane == 63) wsum[wid] = v;
  __syncthreads();
  int add = 0;
  for (int w = 0; w < wid; ++w) add += wsum[w];
  return v + add;
}

// ---------- parallel scan, step 2 ----------
__global__ void scan_chunks_kernel(int* __restrict__ psum, int nc) {
  int i = threadIdx.x;
  int v = (i < nc) ? psum[i] : 0;
  int incl = block_incl_scan_256(v);
  if (i < nc) psum[i] = incl;
}

// ---------- parallel scan, step 3 ----------
__global__ void scan_final_kernel(const int* __restrict__ deg, const int* __restrict__ psum,
                                  int* __restrict__ rowptr, int n) {
  int c = blockIdx.x;
  int i = c * 256 + threadIdx.x;
  int v = (i < n) ? deg[i] : 0;
  int incl = block_incl_scan_256(v);
  int off = (c > 0) ? psum[c - 1] : 0;
  if (i < n) rowptr[i + 1] = off + incl;
  if (i == 0) rowptr[0] = 0;
}

// ---------- CSR build: fill src ids into dst buckets ----------
__global__ void fill_kernel(const int* __restrict__ ei, int* __restrict__ cnt,
                            const int* __restrict__ rowptr, int* __restrict__ ebuf,
                            int nE, int nN) {
  int t = blockIdx.x * blockDim.x + threadIdx.x;
  if (t >= nE + nN) return;
  int s, d;
  if (t < nE) { s = ei[t]; d = ei[nE + t]; } else { s = t - nE; d = s; }
  int pos = rowptr[d] + atomicAdd(&cnt[d], 1);
  ebuf[pos] = s;
}

// ---------- fused GATv2 layer: wave per dst, 4x16-lane edge groups ----------
template<int H, typename OutT>
__global__ void gat_fused_kernel(const __half* __restrict__ XL, const float* __restrict__ XR,
                                 const int* __restrict__ rowptr, const int* __restrict__ ebuf,
                                 const float* __restrict__ att, const float* __restrict__ bias,
                                 OutT* __restrict__ out, int nN) {
  constexpr bool HAS2 = (H > 64);
  int lane = threadIdx.x & 63;
  int wid = threadIdx.x >> 6;
  int d = blockIdx.x * (blockDim.x >> 6) + wid;
  if (d >= nN) return;
  int g = lane >> 4;
  int ll = lane & 15;
  const int cA = ll * 4;
  const int cB = 64 + ll * 2;

  const float* xrrow = XR + (size_t)d * H;
  float4 xr4 = *(const float4*)(xrrow + cA);
  float4 a4 = *(const float4*)(att + cA);
  float4 s4 = make_float4(a4.x * NEG_SLOPE, a4.y * NEG_SLOPE, a4.z * NEG_SLOPE, a4.w * NEG_SLOPE);
  float2 xr2 = make_float2(0.f, 0.f), a2 = make_float2(0.f, 0.f), s2 = make_float2(0.f, 0.f);
  if constexpr (HAS2) {
    xr2 = *(const float2*)(xrrow + cB);
    a2 = *(const float2*)(att + cB);
    s2 = make_float2(a2.x * NEG_SLOPE, a2.y * NEG_SLOPE);
  }

  float m = -1e30f, den = 0.f;
  float4 o4 = make_float4(0.f, 0.f, 0.f, 0.f);
  float2 o2 = make_float2(0.f, 0.f);

  int beg = rowptr[d], end = rowptr[d + 1];
  int i = beg + g;
  int s = (i < end) ? ebuf[i] : 0;
  while (i < end) {
    int inext = i + 4;
    int snext = (inext < end) ? ebuf[inext] : 0;
    const __half* R = XL + (size_t)s * H;
    uint2 ua = *(const uint2*)(R + cA);
    float2 fa0 = __half22float2(u2h2(ua.x));
    float2 fa1 = __half22float2(u2h2(ua.y));
    float4 x4 = make_float4(fa0.x, fa0.y, fa1.x, fa1.y);
    float2 x2 = make_float2(0.f, 0.f);
    if constexpr (HAS2) {
      unsigned ub = *(const unsigned*)(R + cB);
      x2 = __half22float2(u2h2(ub));
    }
    float f, p;
    f = x4.x + xr4.x; p = fmaf(fmaxf(f, 0.f), a4.x, fminf(f, 0.f) * s4.x);
    f = x4.y + xr4.y; p = fmaf(fmaxf(f, 0.f), a4.y, fmaf(fminf(f, 0.f), s4.y, p));
    f = x4.z + xr4.z; p = fmaf(fmaxf(f, 0.f), a4.z, fmaf(fminf(f, 0.f), s4.z, p));
    f = x4.w + xr4.w; p = fmaf(fmaxf(f, 0.f), a4.w, fmaf(fminf(f, 0.f), s4.w, p));
    if constexpr (HAS2) {
      f = x2.x + xr2.x; p = fmaf(fmaxf(f, 0.f), a2.x, fmaf(fminf(f, 0.f), s2.x, p));
      f = x2.y + xr2.y; p = fmaf(fmaxf(f, 0.f), a2.y, fmaf(fminf(f, 0.f), s2.y, p));
    }
    p += __shfl_xor(p, 1);
    p += __shfl_xor(p, 2);
    p += __shfl_xor(p, 4);
    p += __shfl_xor(p, 8);
    if (p > m) {
      float scl = __expf(m - p);
      den *= scl;
      o4.x *= scl; o4.y *= scl; o4.z *= scl; o4.w *= scl;
      if constexpr (HAS2) { o2.x *= scl; o2.y *= scl; }
      m = p;
    }
    float w = __expf(p - m);
    den += w;
    o4.x = fmaf(w, x4.x, o4.x); o4.y = fmaf(w, x4.y, o4.y);
    o4.z = fmaf(w, x4.z, o4.z); o4.w = fmaf(w, x4.w, o4.w);
    if constexpr (HAS2) { o2.x = fmaf(w, x2.x, o2.x); o2.y = fmaf(w, x2.y, o2.y); }
    i = inext;
    s = snext;
  }

#pragma unroll
  for (int msk = 16; msk <= 32; msk <<= 1) {
    float m2 = __shfl_xor(m, msk);
    float den2 = __shfl_xor(den, msk);
    float q0 = __shfl_xor(o4.x, msk), q1 = __shfl_xor(o4.y, msk);
    float q2 = __shfl_xor(o4.z, msk), q3 = __shfl_xor(o4.w, msk);
    float q4 = 0.f, q5 = 0.f;
    if constexpr (HAS2) { q4 = __shfl_xor(o2.x, msk); q5 = __shfl_xor(o2.y, msk); }
    float M = fmaxf(m, m2);
    float sa = __expf(m - M), sb = __expf(m2 - M);
    den = den * sa + den2 * sb;
    o4.x = o4.x * sa + q0 * sb; o4.y = o4.y * sa + q1 * sb;
    o4.z = o4.z * sa + q2 * sb; o4.w = o4.w * sa + q3 * sb;
    if constexpr (HAS2) { o2.x = o2.x * sa + q4 * sb; o2.y = o2.y * sa + q5 * sb; }
    m = M;
  }

  if (g == 0) {
    float inv = 1.f / (den + 1e-16f);
    float4 b4 = *(const float4*)(bias + cA);
    float4 y;
    y.x = fmaf(o4.x, inv, b4.x); y.x = y.x > 0.f ? y.x : 0.f;
    y.y = fmaf(o4.y, inv, b4.y); y.y = y.y > 0.f ? y.y : 0.f;
    y.z = fmaf(o4.z, inv, b4.z); y.z = y.z > 0.f ? y.z : 0.f;
    y.w = fmaf(o4.w, inv, b4.w); y.w = y.w > 0.f ? y.w : 0.f;
    if constexpr (__hip_internal::is_same<OutT, float>::value) {
      *(float4*)(out + (size_t)d * H + cA) = y;
      if constexpr (HAS2) {
        float2 b2 = *(const float2*)(bias + cB);
        float2 z;
        z.x = fmaf(o2.x, inv, b2.x); z.x = z.x > 0.f ? z.x : 0.f;
        z.y = fmaf(o2.y, inv, b2.y); z.y = z.y > 0.f ? z.y : 0.f;
        *(float2*)(out + (size_t)d * H + cB) = z;
      }
    } else {
      uint2 uv;
      uv.x = h22u(__floats2half2_rn(y.x, y.y));
      uv.y = h22u(__floats2half2_rn(y.z, y.w));
      *(uint2*)((__half*)out + (size_t)d * H + cA) = uv;
      if constexpr (HAS2) {
        float2 b2 = *(const float2*)(bias + cB);
        float zx = fmaf(o2.x, inv, b2.x); zx = zx > 0.f ? zx : 0.f;
        float zy = fmaf(o2.y, inv, b2.y); zy = zy > 0.f ? zy : 0.f;
        *(unsigned*)((__half*)out + (size_t)d * H + cB) = h22u(__floats2half2_rn(zx, zy));
      }
    }
  }
}

// ---------- predict: 4 labels/wave, 16-lane groups, coalesced 128B row reads ----------
// lane ll owns channels 4ll..4ll+3 (uint2 per row); group reduce = 4 shfl steps.
__global__ void predict_kernel(const __half* __restrict__ h, const int* __restrict__ eli,
                               const float* __restrict__ Wp, const float* __restrict__ bp,
                               float* __restrict__ out, int L) {
  int lane = threadIdx.x & 63;
  int wv = threadIdx.x >> 6;
  int g = lane >> 4, ll = lane & 15;
  int l = (blockIdx.x * (blockDim.x >> 6) + wv) * 4 + g;
  if (l >= L) return;
  int s = eli[l], d = eli[L + l];
  uint2 us = *(const uint2*)(h + (size_t)s * 64 + 4 * ll);
  uint2 ud = *(const uint2*)(h + (size_t)d * 64 + 4 * ll);
  float2 s0 = __half22float2(u2h2(us.x)), s1 = __half22float2(u2h2(us.y));
  float2 e0 = __half22float2(u2h2(ud.x)), e1 = __half22float2(u2h2(ud.y));
  float4 w0 = ((const float4*)Wp)[2 * ll];      // (w[4ll,0],w[4ll,1],w[4ll+1,0],w[4ll+1,1])
  float4 w1 = ((const float4*)Wp)[2 * ll + 1];  // k = 4ll+2, 4ll+3
  float acc;
  acc = (s0.x * e0.x) * (w0.x + w0.y);
  acc = fmaf(s0.y * e0.y, w0.z + w0.w, acc);
  acc = fmaf(s1.x * e1.x, w1.x + w1.y, acc);
  acc = fmaf(s1.y * e1.y, w1.z + w1.w, acc);
  acc += __shfl_xor(acc, 1);
  acc += __shfl_xor(acc, 2);
  acc += __shfl_xor(acc, 4);
  acc += __shfl_xor(acc, 8);
  if (ll == 0) out[l] = acc + bp[0] + bp[1];
}

static inline int cdiv(long long a, int b) { return (int)((a + b - 1) / b); }

extern "C" void kernel_launch(void* const* d_in, const int* in_sizes, int n_in,
                              void* d_out, int out_size, void* d_ws, size_t ws_size,
                              hipStream_t stream) {
  const float* x    = (const float*)d_in[0];
  const int*   ei   = (const int*)d_in[1];
  const int*   eli  = (const int*)d_in[2];
  const float* Wl1  = (const float*)d_in[3];
  const float* Wr1  = (const float*)d_in[4];
  const float* att1 = (const float*)d_in[5];
  const float* b1   = (const float*)d_in[6];
  const float* Wl2  = (const float*)d_in[7];
  const float* Wr2  = (const float*)d_in[8];
  const float* att2 = (const float*)d_in[9];
  const float* b2   = (const float*)d_in[10];
  const float* Wp   = (const float*)d_in[11];
  const float* bp   = (const float*)d_in[12];
  float* out = (float*)d_out;

  const int N = in_sizes[0] / 128;
  const int E = in_sizes[1] / 2;
  const int L = in_sizes[2] / 2;
  const int T = E + N;
  const int NC = cdiv(N, 256);

  // workspace layout (all 16B-aligned)
  _Float16* xh   = (_Float16*)d_ws;                     // [N*128] fp16 x
  __half* xlh    = (__half*)(xh + (size_t)N * 128);     // [N*96] gather table
  float* xr      = (float*)(xlh + (size_t)N * 96);      // [N*96] fp32 xr
  __half* h1h    = (__half*)(xr + (size_t)N * 96);      // [N*96] fp16 h1
  __half* h2h    = h1h + (size_t)N * 96;                // [N*64] fp16 h2
  _Float16* wt1a = (_Float16*)(h2h + (size_t)N * 64);   // [96*132] Wl1^T fp16
  _Float16* wt1b = wt1a + 96 * 132;                     // [96*132] Wr1^T fp16
  _Float16* wt2a = wt1b + 96 * 132;                     // [64*100] Wl2^T fp16
  _Float16* wt2b = wt2a + 64 * 100;                     // [64*100] Wr2^T fp16
  int* deg       = (int*)(wt2b + 64 * 100);             // [N]
  int* cnt       = deg + N;                             // [N]
  int* rowptr    = cnt + N;                             // [N+1]
  int* ebuf      = rowptr + N + 1;                      // [T]
  int* psum      = ebuf + T;                            // [NC]

  const int BS = 256;
  const int GB64 = cdiv(N, 64);
  const int nbHist = cdiv(T, BS);
  const int nbCvt = cdiv((long long)N * 32, BS);
  const int nbW = cdiv(2 * 128 * 96 + 2 * 96 * 64, BS);

  // ---------------- fused prep (hist + cvt + wtrans x4) ----------------
  (void)hipMemsetAsync(deg, 0, (size_t)(2 * N) * 4, stream);  // deg + cnt
  prep_kernel<<<nbHist + nbCvt + nbW, BS, 0, stream>>>(
      ei, deg, E, N, x, xh, N * 32,
      Wl1, Wr1, wt1a, wt1b, Wl2, Wr2, wt2a, wt2b, nbHist, nbCvt);
  chunk_sum_kernel<<<NC, 256, 0, stream>>>(deg, psum, N);
  scan_chunks_kernel<<<1, 256, 0, stream>>>(psum, NC);
  scan_final_kernel<<<NC, 256, 0, stream>>>(deg, psum, rowptr, N);
  fill_kernel<<<cdiv(T, BS), BS, 0, stream>>>(ei, cnt, rowptr, ebuf, E, N);

  // ---------------- layer 1 (128 -> 96), MFMA ----------------
  gemm2_mfma_kernel<128, 96><<<GB64, 256, 0, stream>>>(xh, wt1a, wt1b, xlh, xr, N);
  gat_fused_kernel<96, __half><<<cdiv(N, BS / 64), BS, 0, stream>>>(xlh, xr, rowptr, ebuf, att1, b1, h1h, N);

  // ---------------- layer 2 (96 -> 64), MFMA ----------------
  gemm2_mfma_kernel<96, 64><<<GB64, 256, 0, stream>>>((const _Float16*)h1h, wt2a, wt2b, xlh, xr, N);
  gat_fused_kernel<64, __half><<<cdiv(N, BS / 64), BS, 0, stream>>>(xlh, xr, rowptr, ebuf, att2, b2, h2h, N);

  // ---------------- link predictor ----------------
  predict_kernel<<<cdiv(L, BS / 64 * 4), BS, 0, stream>>>(h2h, eli, Wp, bp, out, L);
}

// Round 23
// 194.754 us; speedup vs baseline: 1.4649x; 1.1425x over previous
//
#include <hip/hip_runtime.h>
#include <hip/hip_fp16.h>

#define NEG_SLOPE 0.2f

typedef _Float16 half8_t __attribute__((ext_vector_type(8)));
typedef _Float16 half4_t __attribute__((ext_vector_type(4)));
typedef float f32x4 __attribute__((ext_vector_type(4)));

__device__ __forceinline__ __half2 u2h2(unsigned u) {
  union { unsigned u; __half2 h; } cv; cv.u = u; return cv.h;
}
__device__ __forceinline__ unsigned h22u(__half2 h) {
  union { unsigned u; __half2 h; } cv; cv.h = h; return cv.u;
}

// ---------- fused prep: hist(+slot) + x->fp16 + 4x W-transpose ----------
// hist records each edge's within-bucket slot (atomicAdd return) so fill
// needs no atomic. Block ranges partition the work.
__global__ void prep_kernel(const int* __restrict__ ei, int* __restrict__ deg,
                            int* __restrict__ slot, int nE, int nN,
                            const float* __restrict__ x, _Float16* __restrict__ xh, int n4,
                            const float* __restrict__ Wl1, const float* __restrict__ Wr1,
                            _Float16* __restrict__ wt1a, _Float16* __restrict__ wt1b,
                            const float* __restrict__ Wl2, const float* __restrict__ Wr2,
                            _Float16* __restrict__ wt2a, _Float16* __restrict__ wt2b,
                            int nbHist, int nbCvt) {
  int b = blockIdx.x;
  if (b < nbHist) {
    int t = b * 256 + threadIdx.x;
    if (t < nE + nN) {
      int d = (t < nE) ? ei[nE + t] : (t - nE);
      slot[t] = atomicAdd(&deg[d], 1);
    }
  } else if (b < nbHist + nbCvt) {
    int i = (b - nbHist) * 256 + threadIdx.x;
    if (i < n4) {
      float4 v = ((const float4*)x)[i];
      half4_t h = { (_Float16)v.x, (_Float16)v.y, (_Float16)v.z, (_Float16)v.w };
      ((half4_t*)xh)[i] = h;
    }
  } else {
    constexpr int SZ1 = 128 * 96, SZ2 = 96 * 64;
    int idx = (b - nbHist - nbCvt) * 256 + threadIdx.x;
    if (idx < SZ1) {
      int k = idx / 96, h = idx - k * 96;
      wt1a[h * 132 + k] = (_Float16)Wl1[idx];
    } else if (idx < 2 * SZ1) {
      int j = idx - SZ1; int k = j / 96, h = j - k * 96;
      wt1b[h * 132 + k] = (_Float16)Wr1[j];
    } else if (idx < 2 * SZ1 + SZ2) {
      int j = idx - 2 * SZ1; int k = j / 64, h = j - k * 64;
      wt2a[h * 100 + k] = (_Float16)Wl2[j];
    } else if (idx < 2 * SZ1 + 2 * SZ2) {
      int j = idx - 2 * SZ1 - SZ2; int k = j / 64, h = j - k * 64;
      wt2b[h * 100 + k] = (_Float16)Wr2[j];
    }
  }
}

// ---------- dual-output MFMA GEMM (fp16 in, f32 acc): Y1(fp16)=X@W1, Y2(f32)=X@W2 ----------
// Fragment maps (VERIFIED rounds 18/19): A row=lane&15, k=kt*32+(lane>>4)*4+(j&3)+(j>>2)*16;
// C/D col=lane&15, row=(lane>>4)*4+j.
template<int K, int H>
__global__ __launch_bounds__(256) void gemm2_mfma_kernel(const _Float16* __restrict__ Xh,
                                                         const _Float16* __restrict__ Wt1,
                                                         const _Float16* __restrict__ Wt2,
                                                         __half* __restrict__ Y1,
                                                         float* __restrict__ Y2, int n) {
  constexpr int KP = K + 4;
  constexpr int KT = K / 32;
  constexpr int CT = H / 16;
  constexpr int WB = H * KP;
  __shared__ _Float16 Ws1[WB];
  __shared__ _Float16 Ws2[WB];
  const int tid = threadIdx.x;
  for (int i = tid; i < WB / 8; i += 256) {
    ((uint4*)Ws1)[i] = ((const uint4*)Wt1)[i];
    ((uint4*)Ws2)[i] = ((const uint4*)Wt2)[i];
  }
  __syncthreads();
  const int wv = tid >> 6, lane = tid & 63;
  const int q = lane >> 4, c = lane & 15;
  const int r0 = blockIdx.x * 64 + wv * 16;
  if (r0 >= n) return;
  int arow = r0 + c; if (arow >= n) arow = n - 1;
  const _Float16* Xrow = Xh + (size_t)arow * K;
  half8_t A[KT];
#pragma unroll
  for (int kt = 0; kt < KT; ++kt) {
    half4_t lo = *(const half4_t*)(Xrow + kt * 32 + q * 4);
    half4_t hi = *(const half4_t*)(Xrow + kt * 32 + 16 + q * 4);
    A[kt] = __builtin_shufflevector(lo, hi, 0, 1, 2, 3, 4, 5, 6, 7);
  }
#pragma unroll
  for (int ct = 0; ct < CT; ++ct) {
    const int col = ct * 16 + c;
    f32x4 acc1 = {0.f, 0.f, 0.f, 0.f};
    f32x4 acc2 = {0.f, 0.f, 0.f, 0.f};
#pragma unroll
    for (int kt = 0; kt < KT; ++kt) {
      const _Float16* w1p = &Ws1[col * KP + kt * 32 + q * 4];
      const _Float16* w2p = &Ws2[col * KP + kt * 32 + q * 4];
      half4_t b1lo = *(const half4_t*)w1p;
      half4_t b1hi = *(const half4_t*)(w1p + 16);
      half4_t b2lo = *(const half4_t*)w2p;
      half4_t b2hi = *(const half4_t*)(w2p + 16);
      half8_t B1 = __builtin_shufflevector(b1lo, b1hi, 0, 1, 2, 3, 4, 5, 6, 7);
      half8_t B2 = __builtin_shufflevector(b2lo, b2hi, 0, 1, 2, 3, 4, 5, 6, 7);
      acc1 = __builtin_amdgcn_mfma_f32_16x16x32_f16(A[kt], B1, acc1, 0, 0, 0);
      acc2 = __builtin_amdgcn_mfma_f32_16x16x32_f16(A[kt], B2, acc2, 0, 0, 0);
    }
#pragma unroll
    for (int j = 0; j < 4; ++j) {
      int rowg = r0 + q * 4 + j;
      if (rowg < n) {
        Y1[(size_t)rowg * H + col] = __float2half(acc1[j]);
        Y2[(size_t)rowg * H + col] = acc2[j];
      }
    }
  }
}

// ---------- parallel scan, step 1: per-256-chunk sums ----------
__global__ void chunk_sum_kernel(const int* __restrict__ deg, int* __restrict__ psum, int n) {
  int c = blockIdx.x;
  int i = c * 256 + threadIdx.x;
  int lane = threadIdx.x & 63, wid = threadIdx.x >> 6;
  int v = (i < n) ? deg[i] : 0;
#pragma unroll
  for (int off = 32; off; off >>= 1) v += __shfl_xor(v, off);
  __shared__ int ws[4];
  if (lane == 0) ws[wid] = v;
  __syncthreads();
  if (threadIdx.x == 0) psum[c] = ws[0] + ws[1] + ws[2] + ws[3];
}

// ---------- block-wide inclusive scan helper (256 threads) ----------
__device__ __forceinline__ int block_incl_scan_256(int v) {
  int lane = threadIdx.x & 63, wid = threadIdx.x >> 6;
#pragma unroll
  for (int off = 1; off < 64; off <<= 1) {
    int t = __shfl_up(v, off);
    if (lane >= off) v += t;
  }
  __shared__ int wsum[4];
  if (lane == 63) wsum[wid] = v;
  __syncthreads();
  int add = 0;
  for (int w = 0; w < wid; ++w) add += wsum[w];
  return v + add;
}

// ---------- parallel scan, step 2 ----------
__global__ void scan_chunks_kernel(int* __restrict__ psum, int nc) {
  int i = threadIdx.x;
  int v = (i < nc) ? psum[i] : 0;
  int incl = block_incl_scan_256(v);
  if (i < nc) psum[i] = incl;
}

// ---------- parallel scan, step 3 ----------
__global__ void scan_final_kernel(const int* __restrict__ deg, const int* __restrict__ psum,
                                  int* __restrict__ rowptr, int n) {
  int c = blockIdx.x;
  int i = c * 256 + threadIdx.x;
  int v = (i < n) ? deg[i] : 0;
  int incl = block_incl_scan_256(v);
  int off = (c > 0) ? psum[c - 1] : 0;
  if (i < n) rowptr[i + 1] = off + incl;
  if (i == 0) rowptr[0] = 0;
}

// ---------- CSR fill: NO atomic — slot precomputed in prep ----------
__global__ void fill_kernel(const int* __restrict__ ei, const int* __restrict__ slot,
                            const int* __restrict__ rowptr, int* __restrict__ ebuf,
                            int nE, int nN) {
  int t = blockIdx.x * blockDim.x + threadIdx.x;
  if (t >= nE + nN) return;
  int s, d;
  if (t < nE) { s = ei[t]; d = ei[nE + t]; } else { s = t - nE; d = s; }
  ebuf[rowptr[d] + slot[t]] = s;
}

// ---------- fused GATv2 layer: wave per dst, 4x16-lane edge groups ----------
template<int H, typename OutT>
__global__ void gat_fused_kernel(const __half* __restrict__ XL, const float* __restrict__ XR,
                                 const int* __restrict__ rowptr, const int* __restrict__ ebuf,
                                 const float* __restrict__ att, const float* __restrict__ bias,
                                 OutT* __restrict__ out, int nN) {
  constexpr bool HAS2 = (H > 64);
  int lane = threadIdx.x & 63;
  int wid = threadIdx.x >> 6;
  int d = blockIdx.x * (blockDim.x >> 6) + wid;
  if (d >= nN) return;
  int g = lane >> 4;
  int ll = lane & 15;
  const int cA = ll * 4;
  const int cB = 64 + ll * 2;

  const float* xrrow = XR + (size_t)d * H;
  float4 xr4 = *(const float4*)(xrrow + cA);
  float4 a4 = *(const float4*)(att + cA);
  float4 s4 = make_float4(a4.x * NEG_SLOPE, a4.y * NEG_SLOPE, a4.z * NEG_SLOPE, a4.w * NEG_SLOPE);
  float2 xr2 = make_float2(0.f, 0.f), a2 = make_float2(0.f, 0.f), s2 = make_float2(0.f, 0.f);
  if constexpr (HAS2) {
    xr2 = *(const float2*)(xrrow + cB);
    a2 = *(const float2*)(att + cB);
    s2 = make_float2(a2.x * NEG_SLOPE, a2.y * NEG_SLOPE);
  }

  float m = -1e30f, den = 0.f;
  float4 o4 = make_float4(0.f, 0.f, 0.f, 0.f);
  float2 o2 = make_float2(0.f, 0.f);

  int beg = rowptr[d], end = rowptr[d + 1];
  int i = beg + g;
  int s = (i < end) ? ebuf[i] : 0;
  while (i < end) {
    int inext = i + 4;
    int snext = (inext < end) ? ebuf[inext] : 0;
    const __half* R = XL + (size_t)s * H;
    uint2 ua = *(const uint2*)(R + cA);
    float2 fa0 = __half22float2(u2h2(ua.x));
    float2 fa1 = __half22float2(u2h2(ua.y));
    float4 x4 = make_float4(fa0.x, fa0.y, fa1.x, fa1.y);
    float2 x2 = make_float2(0.f, 0.f);
    if constexpr (HAS2) {
      unsigned ub = *(const unsigned*)(R + cB);
      x2 = __half22float2(u2h2(ub));
    }
    float f, p;
    f = x4.x + xr4.x; p = fmaf(fmaxf(f, 0.f), a4.x, fminf(f, 0.f) * s4.x);
    f = x4.y + xr4.y; p = fmaf(fmaxf(f, 0.f), a4.y, fmaf(fminf(f, 0.f), s4.y, p));
    f = x4.z + xr4.z; p = fmaf(fmaxf(f, 0.f), a4.z, fmaf(fminf(f, 0.f), s4.z, p));
    f = x4.w + xr4.w; p = fmaf(fmaxf(f, 0.f), a4.w, fmaf(fminf(f, 0.f), s4.w, p));
    if constexpr (HAS2) {
      f = x2.x + xr2.x; p = fmaf(fmaxf(f, 0.f), a2.x, fmaf(fminf(f, 0.f), s2.x, p));
      f = x2.y + xr2.y; p = fmaf(fmaxf(f, 0.f), a2.y, fmaf(fminf(f, 0.f), s2.y, p));
    }
    p += __shfl_xor(p, 1);
    p += __shfl_xor(p, 2);
    p += __shfl_xor(p, 4);
    p += __shfl_xor(p, 8);
    if (p > m) {
      float scl = __expf(m - p);
      den *= scl;
      o4.x *= scl; o4.y *= scl; o4.z *= scl; o4.w *= scl;
      if constexpr (HAS2) { o2.x *= scl; o2.y *= scl; }
      m = p;
    }
    float w = __expf(p - m);
    den += w;
    o4.x = fmaf(w, x4.x, o4.x); o4.y = fmaf(w, x4.y, o4.y);
    o4.z = fmaf(w, x4.z, o4.z); o4.w = fmaf(w, x4.w, o4.w);
    if constexpr (HAS2) { o2.x = fmaf(w, x2.x, o2.x); o2.y = fmaf(w, x2.y, o2.y); }
    i = inext;
    s = snext;
  }

#pragma unroll
  for (int msk = 16; msk <= 32; msk <<= 1) {
    float m2 = __shfl_xor(m, msk);
    float den2 = __shfl_xor(den, msk);
    float q0 = __shfl_xor(o4.x, msk), q1 = __shfl_xor(o4.y, msk);
    float q2 = __shfl_xor(o4.z, msk), q3 = __shfl_xor(o4.w, msk);
    float q4 = 0.f, q5 = 0.f;
    if constexpr (HAS2) { q4 = __shfl_xor(o2.x, msk); q5 = __shfl_xor(o2.y, msk); }
    float M = fmaxf(m, m2);
    float sa = __expf(m - M), sb = __expf(m2 - M);
    den = den * sa + den2 * sb;
    o4.x = o4.x * sa + q0 * sb; o4.y = o4.y * sa + q1 * sb;
    o4.z = o4.z * sa + q2 * sb; o4.w = o4.w * sa + q3 * sb;
    if constexpr (HAS2) { o2.x = o2.x * sa + q4 * sb; o2.y = o2.y * sa + q5 * sb; }
    m = M;
  }

  if (g == 0) {
    float inv = 1.f / (den + 1e-16f);
    float4 b4 = *(const float4*)(bias + cA);
    float4 y;
    y.x = fmaf(o4.x, inv, b4.x); y.x = y.x > 0.f ? y.x : 0.f;
    y.y = fmaf(o4.y, inv, b4.y); y.y = y.y > 0.f ? y.y : 0.f;
    y.z = fmaf(o4.z, inv, b4.z); y.z = y.z > 0.f ? y.z : 0.f;
    y.w = fmaf(o4.w, inv, b4.w); y.w = y.w > 0.f ? y.w : 0.f;
    if constexpr (__hip_internal::is_same<OutT, float>::value) {
      *(float4*)(out + (size_t)d * H + cA) = y;
      if constexpr (HAS2) {
        float2 b2 = *(const float2*)(bias + cB);
        float2 z;
        z.x = fmaf(o2.x, inv, b2.x); z.x = z.x > 0.f ? z.x : 0.f;
        z.y = fmaf(o2.y, inv, b2.y); z.y = z.y > 0.f ? z.y : 0.f;
        *(float2*)(out + (size_t)d * H + cB) = z;
      }
    } else {
      uint2 uv;
      uv.x = h22u(__floats2half2_rn(y.x, y.y));
      uv.y = h22u(__floats2half2_rn(y.z, y.w));
      *(uint2*)((__half*)out + (size_t)d * H + cA) = uv;
      if constexpr (HAS2) {
        float2 b2 = *(const float2*)(bias + cB);
        float zx = fmaf(o2.x, inv, b2.x); zx = zx > 0.f ? zx : 0.f;
        float zy = fmaf(o2.y, inv, b2.y); zy = zy > 0.f ? zy : 0.f;
        *(unsigned*)((__half*)out + (size_t)d * H + cB) = h22u(__floats2half2_rn(zx, zy));
      }
    }
  }
}

// ---------- predict: 4 labels/wave, 16-lane groups, coalesced 128B row reads ----------
__global__ void predict_kernel(const __half* __restrict__ h, const int* __restrict__ eli,
                               const float* __restrict__ Wp, const float* __restrict__ bp,
                               float* __restrict__ out, int L) {
  int lane = threadIdx.x & 63;
  int wv = threadIdx.x >> 6;
  int g = lane >> 4, ll = lane & 15;
  int l = (blockIdx.x * (blockDim.x >> 6) + wv) * 4 + g;
  if (l >= L) return;
  int s = eli[l], d = eli[L + l];
  uint2 us = *(const uint2*)(h + (size_t)s * 64 + 4 * ll);
  uint2 ud = *(const uint2*)(h + (size_t)d * 64 + 4 * ll);
  float2 s0 = __half22float2(u2h2(us.x)), s1 = __half22float2(u2h2(us.y));
  float2 e0 = __half22float2(u2h2(ud.x)), e1 = __half22float2(u2h2(ud.y));
  float4 w0 = ((const float4*)Wp)[2 * ll];
  float4 w1 = ((const float4*)Wp)[2 * ll + 1];
  float acc;
  acc = (s0.x * e0.x) * (w0.x + w0.y);
  acc = fmaf(s0.y * e0.y, w0.z + w0.w, acc);
  acc = fmaf(s1.x * e1.x, w1.x + w1.y, acc);
  acc = fmaf(s1.y * e1.y, w1.z + w1.w, acc);
  acc += __shfl_xor(acc, 1);
  acc += __shfl_xor(acc, 2);
  acc += __shfl_xor(acc, 4);
  acc += __shfl_xor(acc, 8);
  if (ll == 0) out[l] = acc + bp[0] + bp[1];
}

static inline int cdiv(long long a, int b) { return (int)((a + b - 1) / b); }

extern "C" void kernel_launch(void* const* d_in, const int* in_sizes, int n_in,
                              void* d_out, int out_size, void* d_ws, size_t ws_size,
                              hipStream_t stream) {
  const float* x    = (const float*)d_in[0];
  const int*   ei   = (const int*)d_in[1];
  const int*   eli  = (const int*)d_in[2];
  const float* Wl1  = (const float*)d_in[3];
  const float* Wr1  = (const float*)d_in[4];
  const float* att1 = (const float*)d_in[5];
  const float* b1   = (const float*)d_in[6];
  const float* Wl2  = (const float*)d_in[7];
  const float* Wr2  = (const float*)d_in[8];
  const float* att2 = (const float*)d_in[9];
  const float* b2   = (const float*)d_in[10];
  const float* Wp   = (const float*)d_in[11];
  const float* bp   = (const float*)d_in[12];
  float* out = (float*)d_out;

  const int N = in_sizes[0] / 128;
  const int E = in_sizes[1] / 2;
  const int L = in_sizes[2] / 2;
  const int T = E + N;
  const int NC = cdiv(N, 256);

  // workspace layout (all 16B-aligned)
  _Float16* xh   = (_Float16*)d_ws;                     // [N*128] fp16 x
  __half* xlh    = (__half*)(xh + (size_t)N * 128);     // [N*96] gather table
  float* xr      = (float*)(xlh + (size_t)N * 96);      // [N*96] fp32 xr
  __half* h1h    = (__half*)(xr + (size_t)N * 96);      // [N*96] fp16 h1
  __half* h2h    = h1h + (size_t)N * 96;                // [N*64] fp16 h2
  _Float16* wt1a = (_Float16*)(h2h + (size_t)N * 64);   // [96*132] Wl1^T fp16
  _Float16* wt1b = wt1a + 96 * 132;                     // [96*132] Wr1^T fp16
  _Float16* wt2a = wt1b + 96 * 132;                     // [64*100] Wl2^T fp16
  _Float16* wt2b = wt2a + 64 * 100;                     // [64*100] Wr2^T fp16
  int* deg       = (int*)(wt2b + 64 * 100);             // [N]
  int* slot      = deg + N;                             // [T] within-bucket slot
  int* rowptr    = slot + T;                            // [N+1]
  int* ebuf      = rowptr + N + 1;                      // [T]
  int* psum      = ebuf + T;                            // [NC]

  const int BS = 256;
  const int GB64 = cdiv(N, 64);
  const int nbHist = cdiv(T, BS);
  const int nbCvt = cdiv((long long)N * 32, BS);
  const int nbW = cdiv(2 * 128 * 96 + 2 * 96 * 64, BS);

  // ---------------- fused prep (hist+slot + cvt + wtrans x4) ----------------
  (void)hipMemsetAsync(deg, 0, (size_t)N * 4, stream);
  prep_kernel<<<nbHist + nbCvt + nbW, BS, 0, stream>>>(
      ei, deg, slot, E, N, x, xh, N * 32,
      Wl1, Wr1, wt1a, wt1b, Wl2, Wr2, wt2a, wt2b, nbHist, nbCvt);
  chunk_sum_kernel<<<NC, 256, 0, stream>>>(deg, psum, N);
  scan_chunks_kernel<<<1, 256, 0, stream>>>(psum, NC);
  scan_final_kernel<<<NC, 256, 0, stream>>>(deg, psum, rowptr, N);
  fill_kernel<<<cdiv(T, BS), BS, 0, stream>>>(ei, slot, rowptr, ebuf, E, N);

  // ---------------- layer 1 (128 -> 96), MFMA ----------------
  gemm2_mfma_kernel<128, 96><<<GB64, 256, 0, stream>>>(xh, wt1a, wt1b, xlh, xr, N);
  gat_fused_kernel<96, __half><<<cdiv(N, BS / 64), BS, 0, stream>>>(xlh, xr, rowptr, ebuf, att1, b1, h1h, N);

  // ---------------- layer 2 (96 -> 64), MFMA ----------------
  gemm2_mfma_kernel<96, 64><<<GB64, 256, 0, stream>>>((const _Float16*)h1h, wt2a, wt2b, xlh, xr, N);
  gat_fused_kernel<64, __half><<<cdiv(N, BS / 64), BS, 0, stream>>>(xlh, xr, rowptr, ebuf, att2, b2, h2h, N);

  // ---------------- link predictor ----------------
  predict_kernel<<<cdiv(L, BS / 64 * 4), BS, 0, stream>>>(h2h, eli, Wp, bp, out, L);
}